// Round 1
// baseline (9583.597 us; speedup 1.0000x reference)
//
#include <hip/hip_runtime.h>
#include <cstdint>
#include <cstddef>

// EP-LSTM, B=64 T=1024 D=256 H=256.  I/O dtype: FP32 (per reference file).
// Identity: pre = x@(Wx + W_in@We) + h@(Wh - We) + b   (e@We eliminated).
//
// d_ws is NOT used.  All scratch lives in the y-region of d_out
// (67,108,864 bytes), which is only written by the FINAL kernel:
//   Gc     @ y+0        : [64*256][1024] bf16 = 33,554,432 B (per-chunk G)
//   At     @ y+33554432 : [1024][256] bf16    = 524,288  (A^T = (Wx+W_in@We)^T)
//   Rres   @ y+34078720 : [128][512] u32      = 262,144  (f16x2 pairs, cols 0..511)
//   Rstr2  @ y+34340864 : [128][512] u32      = 262,144  (f16x2 pairs, cols 512..1023)
//   stateH @ y+34603008 : [64][128] u32       = 32,768   (h packed f16x2, chunk carry)
//   stateC @ y+34635776 : [64][256] f32       = 65,536   (c fp32, chunk carry)
//
// v2 scan: ALL recurrent weights on-chip (no per-timestep global streaming).
//   col j        : w[128]  in VGPRs
//   col 512+j    : w2[64]  in VGPRs (k-pairs 0..63) + 64 u32 private LDS slice
//                  (k-pairs 64..127), stride 68 u32 -> conflict-free b128 reads.
//   2 barriers/timestep (was 3): j>=256 exchanges i*g as one f32; h double-
//   buffered as f16 in hb[2][256].

typedef unsigned int   u32;
typedef unsigned short u16;
typedef float  f32x4  __attribute__((ext_vector_type(4)));
typedef short  bf16x8 __attribute__((ext_vector_type(8)));
typedef _Float16 h2_t __attribute__((ext_vector_type(2)));

__device__ __forceinline__ u16 f2bf(float f){
  union { float f; u32 i; } v; v.f = f;
  u32 u = v.i; u32 r = u + 0x7fffu + ((u >> 16) & 1u);
  return (u16)(r >> 16);
}
__device__ __forceinline__ float bf2f(u16 u){
  union { u32 i; float f; } v; v.i = ((u32)u) << 16; return v.f;
}
__device__ __forceinline__ h2_t as_h2(u32 u){
  union { u32 u; h2_t h; } c; c.u = u; return c.h;
}
__device__ __forceinline__ u32 pack_h2(float lo, float hi){
  h2_t h; h.x = (_Float16)lo; h.y = (_Float16)hi;
  union { h2_t h; u32 u; } c; c.h = h; return c.u;
}

#if defined(__has_builtin)
#if __has_builtin(__builtin_amdgcn_fdot2)
#define HAVE_FDOT2 1
#endif
#endif

__device__ __forceinline__ float dot2acc(u32 w, u32 h, float acc){
#ifdef HAVE_FDOT2
  return __builtin_amdgcn_fdot2(as_h2(w), as_h2(h), acc, false);
#else
  h2_t a = as_h2(w), b = as_h2(h);
  acc += (float)a.x * (float)b.x;
  acc += (float)a.y * (float)b.y;
  return acc;
#endif
}

__device__ __forceinline__ float sigf(float x){
  return __builtin_amdgcn_rcpf(1.f + __expf(-x));
}
__device__ __forceinline__ float tanhf_(float x){
  return 2.f * __builtin_amdgcn_rcpf(1.f + __expf(-2.f * x)) - 1.f;
}

// ---------- prep: At[n][k] = Wx[kg][k][j] + sum_m W_in[k][m]*We[kg][m][j] ----------
__global__ void prep_A(const float* __restrict__ Win, const float* __restrict__ Wx,
                       const float* __restrict__ We, u16* __restrict__ At){
  int n  = blockIdx.x;            // 0..1023 (kg*256 + j)
  int kg = n >> 8, j = n & 255;
  int k  = threadIdx.x;           // 0..255 = d
  __shared__ float wec[256];
  wec[k] = We[kg * 65536 + k * 256 + j];   // We[kg][m=k][j]
  __syncthreads();
  float s = Wx[kg * 65536 + k * 256 + j];
  const float* wrow = Win + k * 256;
  #pragma unroll 8
  for (int m = 0; m < 256; m++) s += wrow[m] * wec[m];
  At[n * 256 + k] = f2bf(s);
}

// ---------- prep: R = Wh - We, packed f16x2 by k-pairs, [128][512] per half ----------
__global__ void prep_R(const float* __restrict__ Wh, const float* __restrict__ We,
                       u32* __restrict__ Rres, u32* __restrict__ Rstr2){
  int g   = blockIdx.x * 512 + threadIdx.x;   // 0..131071
  int k2  = g >> 10, col = g & 1023;
  int kg  = col >> 8, j = col & 255;
  int base = kg * 65536 + (2 * k2) * 256 + j;
  float lo = Wh[base]       - We[base];
  float hi = Wh[base + 256] - We[base + 256];
  u32 u = pack_h2(lo, hi);
  if (col < 512) Rres[k2 * 512 + col] = u;
  else           Rstr2[k2 * 512 + (col - 512)] = u;
}

// ---------- gemm_g: Gc[m][n] = bf16( x[srow(m)][:] ) . At[n][:] + bg[n] ----------
__global__ __launch_bounds__(256, 2) void gemm_g(
    const float* __restrict__ X, const u16* __restrict__ At,
    u16* __restrict__ Gc, const float* __restrict__ bg, int t0){
  __shared__ u16 As[64 * 256];
  __shared__ u16 Bs[64 * 256];
  int tid = threadIdx.x;
  int bm = blockIdx.x, bn = blockIdx.y;
  int r = tid >> 2, q = tid & 3;
  int m = bm * 64 + r;
  long srow = (long)(m >> 8) * 1024 + t0 + (m & 255);
  const float* ga = X + srow * 256 + q * 64;
  const u16*   gb = At + ((long)bn * 64 + r) * 256 + q * 64;
  u16* la = As + r * 256 + q * 64;
  u16* lb = Bs + r * 256 + q * 64;
  #pragma unroll
  for (int i = 0; i < 8; i++){
    float4 f0 = *(const float4*)(ga + i * 8);
    float4 f1 = *(const float4*)(ga + i * 8 + 4);
    union { u16 h[8]; uint4 v; } pk;
    pk.h[0] = f2bf(f0.x); pk.h[1] = f2bf(f0.y); pk.h[2] = f2bf(f0.z); pk.h[3] = f2bf(f0.w);
    pk.h[4] = f2bf(f1.x); pk.h[5] = f2bf(f1.y); pk.h[6] = f2bf(f1.z); pk.h[7] = f2bf(f1.w);
    *(uint4*)(la + i * 8) = pk.v;
    *(uint4*)(lb + i * 8) = *(const uint4*)(gb + i * 8);
  }
  __syncthreads();

  int wave = tid >> 6, lane = tid & 63;
  int wm = (wave & 1) * 32, wn = (wave >> 1) * 32;
  int fr = lane & 15, quad = lane >> 4;
  f32x4 acc00 = {0,0,0,0}, acc01 = {0,0,0,0}, acc10 = {0,0,0,0}, acc11 = {0,0,0,0};
  const u16* pa0 = As + (wm + fr) * 256 + quad * 8;
  const u16* pa1 = pa0 + 16 * 256;
  const u16* pb0 = Bs + (wn + fr) * 256 + quad * 8;
  const u16* pb1 = pb0 + 16 * 256;
  #pragma unroll
  for (int k = 0; k < 256; k += 32){
    bf16x8 a0 = *(const bf16x8*)(pa0 + k);
    bf16x8 a1 = *(const bf16x8*)(pa1 + k);
    bf16x8 b0 = *(const bf16x8*)(pb0 + k);
    bf16x8 b1 = *(const bf16x8*)(pb1 + k);
    acc00 = __builtin_amdgcn_mfma_f32_16x16x32_bf16(a0, b0, acc00, 0, 0, 0);
    acc01 = __builtin_amdgcn_mfma_f32_16x16x32_bf16(a0, b1, acc01, 0, 0, 0);
    acc10 = __builtin_amdgcn_mfma_f32_16x16x32_bf16(a1, b0, acc10, 0, 0, 0);
    acc11 = __builtin_amdgcn_mfma_f32_16x16x32_bf16(a1, b1, acc11, 0, 0, 0);
  }
  // C/D layout: col = lane&15, row = (lane>>4)*4 + reg  [m89-verified]
  int cr = quad * 4, cc = fr;
  long rowbase = (long)bm * 64 + wm + cr;
  long colbase = (long)bn * 64 + wn + cc;
  float bias0 = bg[colbase];
  float bias1 = bg[colbase + 16];
  #pragma unroll
  for (int e = 0; e < 4; e++){
    long r0 = rowbase + e, r1 = r0 + 16;
    Gc[r0 * 1024 + colbase]      = f2bf(acc00[e] + bias0);
    Gc[r0 * 1024 + colbase + 16] = f2bf(acc01[e] + bias1);
    Gc[r1 * 1024 + colbase]      = f2bf(acc10[e] + bias0);
    Gc[r1 * 1024 + colbase + 16] = f2bf(acc11[e] + bias1);
  }
}

// ---------- gemm_y: Y[m][n] = hseq[m][:] . W_out[:][n] + bo[n]   (M=65536,N=256) ----------
__global__ __launch_bounds__(256, 2) void gemm_y(
    const float* __restrict__ Hs, const float* __restrict__ Wo,
    float* __restrict__ Y, const float* __restrict__ bo){
  __shared__ u16 As[64 * 256];
  __shared__ u16 Bs[64 * 256];
  int tid = threadIdx.x;
  int bm = blockIdx.x, bn = blockIdx.y;
  int r = tid >> 2, q = tid & 3;
  const float* ga = Hs + ((long)bm * 64 + r) * 256 + q * 64;
  u16* la = As + r * 256 + q * 64;
  #pragma unroll
  for (int i = 0; i < 8; i++){
    float4 f0 = *(const float4*)(ga + i * 8);
    float4 f1 = *(const float4*)(ga + i * 8 + 4);
    union { u16 h[8]; uint4 v; } pk;
    pk.h[0] = f2bf(f0.x); pk.h[1] = f2bf(f0.y); pk.h[2] = f2bf(f0.z); pk.h[3] = f2bf(f0.w);
    pk.h[4] = f2bf(f1.x); pk.h[5] = f2bf(f1.y); pk.h[6] = f2bf(f1.z); pk.h[7] = f2bf(f1.w);
    *(uint4*)(la + i * 8) = pk.v;
  }
  int ncol = bn * 64 + r;
  u16* lb = Bs + r * 256 + q * 64;
  #pragma unroll 8
  for (int i = 0; i < 64; i++) lb[i] = f2bf(Wo[(q * 64 + i) * 256 + ncol]);
  __syncthreads();

  int wave = tid >> 6, lane = tid & 63;
  int wm = (wave & 1) * 32, wn = (wave >> 1) * 32;
  int fr = lane & 15, quad = lane >> 4;
  f32x4 acc00 = {0,0,0,0}, acc01 = {0,0,0,0}, acc10 = {0,0,0,0}, acc11 = {0,0,0,0};
  const u16* pa0 = As + (wm + fr) * 256 + quad * 8;
  const u16* pa1 = pa0 + 16 * 256;
  const u16* pb0 = Bs + (wn + fr) * 256 + quad * 8;
  const u16* pb1 = pb0 + 16 * 256;
  #pragma unroll
  for (int k = 0; k < 256; k += 32){
    bf16x8 a0 = *(const bf16x8*)(pa0 + k);
    bf16x8 a1 = *(const bf16x8*)(pa1 + k);
    bf16x8 b0 = *(const bf16x8*)(pb0 + k);
    bf16x8 b1 = *(const bf16x8*)(pb1 + k);
    acc00 = __builtin_amdgcn_mfma_f32_16x16x32_bf16(a0, b0, acc00, 0, 0, 0);
    acc01 = __builtin_amdgcn_mfma_f32_16x16x32_bf16(a0, b1, acc01, 0, 0, 0);
    acc10 = __builtin_amdgcn_mfma_f32_16x16x32_bf16(a1, b0, acc10, 0, 0, 0);
    acc11 = __builtin_amdgcn_mfma_f32_16x16x32_bf16(a1, b1, acc11, 0, 0, 0);
  }
  int cr = quad * 4, cc = fr;
  long rowbase = (long)bm * 64 + wm + cr;
  long colbase = (long)bn * 64 + wn + cc;
  float bias0 = bo[colbase];
  float bias1 = bo[colbase + 16];
  #pragma unroll
  for (int e = 0; e < 4; e++){
    long r0 = rowbase + e, r1 = r0 + 16;
    Y[r0 * 256 + colbase]      = acc00[e] + bias0;
    Y[r0 * 256 + colbase + 16] = acc01[e] + bias1;
    Y[r1 * 256 + colbase]      = acc10[e] + bias0;
    Y[r1 * 256 + colbase + 16] = acc11[e] + bias1;
  }
}

// ---------- recurrent scan over one 256-step chunk; one WG per batch element ----------
// Thread j owns preact cols j (w, regs) and 512+j (w2 regs k2<64, LDS slice k2>=64).
// j<256: f,o gates + c/h update.  j>=256: i,g gates, exchanges i*g (one f32).
__global__ __launch_bounds__(512, 2) void scan_chunk(
    const u32* __restrict__ Rres, const u32* __restrict__ Rstr2,
    const u16* __restrict__ Gc,
    const float* __restrict__ h0, const float* __restrict__ c0,
    u32* __restrict__ stateH, float* __restrict__ stateC,
    float* __restrict__ hseq, float* __restrict__ cseq, int t0){
  const int CT = 256;
  const int LSTR = 68;                       // 64 u32 payload + 4 pad: bank stride 4
  int b = blockIdx.x;
  int j = threadIdx.x;

  __shared__ __align__(16) u32 Lw[512 * LSTR];   // 139,264 B: k-pairs 64..127 of col 512+j
  __shared__ __align__(16) u16 hb[2][256];       // double-buffered h (f16)
  __shared__ float xch[256];                     // i*g exchange

  u32* mys = Lw + j * LSTR;

  // resident weights: col j fully (128 words) + col 512+j first 64 k-pairs
  u32 w[128];
  #pragma unroll
  for (int k2 = 0; k2 < 128; k2++) w[k2] = Rres[k2 * 512 + j];
  u32 w2[64];
  #pragma unroll
  for (int i = 0; i < 64; i++) w2[i] = Rstr2[i * 512 + j];
  // private LDS slice: col 512+j, k-pairs 64..127
  #pragma unroll
  for (int i = 0; i < 64; i++) mys[i] = Rstr2[(64 + i) * 512 + j];

  float cst = 0.f;
  if (t0 == 0){
    if (j < 128) ((u32*)hb[0])[j] = pack_h2(h0[b * 256 + 2 * j], h0[b * 256 + 2 * j + 1]);
    if (j < 256) cst = c0[b * 256 + j];
  } else {
    if (j < 128) ((u32*)hb[0])[j] = stateH[b * 128 + j];
    if (j < 256) cst = stateC[b * 256 + j];
  }

  const u16* Grow = Gc + (size_t)b * CT * 1024;
  u16 ga = Grow[j], gb = Grow[512 + j];
  __syncthreads();

  int p = 0;
  for (int tt = 0; tt < CT; tt++){
    const u16* Gn = Grow + (size_t)(tt + 1 < CT ? tt + 1 : tt) * 1024;
    u16 gan = Gn[j], gbn = Gn[512 + j];

    float acc0 = bf2f(ga), acc1 = bf2f(gb);   // bias folded into G
    const u16* hrow = hb[p];
    #pragma unroll
    for (int qk = 0; qk < 16; qk++){
      uint4 hh = *(const uint4*)(hrow + qk * 8);
      acc0 = dot2acc(w[4 * qk + 0], hh.x, acc0);
      acc0 = dot2acc(w[4 * qk + 1], hh.y, acc0);
      acc0 = dot2acc(w[4 * qk + 2], hh.z, acc0);
      acc0 = dot2acc(w[4 * qk + 3], hh.w, acc0);
      acc1 = dot2acc(w2[4 * qk + 0], hh.x, acc1);
      acc1 = dot2acc(w2[4 * qk + 1], hh.y, acc1);
      acc1 = dot2acc(w2[4 * qk + 2], hh.z, acc1);
      acc1 = dot2acc(w2[4 * qk + 3], hh.w, acc1);
    }
    #pragma unroll
    for (int qk = 0; qk < 16; qk++){
      uint4 hh = *(const uint4*)(hrow + 128 + qk * 8);
      uint4 ws = *(const uint4*)(mys + 4 * qk);
      acc0 = dot2acc(w[64 + 4 * qk + 0], hh.x, acc0);
      acc0 = dot2acc(w[64 + 4 * qk + 1], hh.y, acc0);
      acc0 = dot2acc(w[64 + 4 * qk + 2], hh.z, acc0);
      acc0 = dot2acc(w[64 + 4 * qk + 3], hh.w, acc0);
      acc1 = dot2acc(ws.x, hh.x, acc1);
      acc1 = dot2acc(ws.y, hh.y, acc1);
      acc1 = dot2acc(ws.z, hh.z, acc1);
      acc1 = dot2acc(ws.w, hh.w, acc1);
    }

    float f = 0.f, o = 0.f;
    if (j >= 256){
      // acc0 = i-gate preact, acc1 = g-gate preact
      xch[j - 256] = sigf(acc0) * tanhf_(acc1);
    } else {
      f = sigf(acc0);
      o = sigf(acc1);
    }
    __syncthreads();

    if (j < 256){
      cst = f * cst + xch[j];
      float hv = o * tanhf_(cst);
      size_t orow = ((size_t)b * 1024 + t0 + tt) * 256 + j;
      hseq[orow] = hv;
      cseq[orow] = cst;
      union { _Float16 h; u16 u; } cv; cv.h = (_Float16)hv;
      hb[p ^ 1][j] = cv.u;
    }
    __syncthreads();

    ga = gan; gb = gbn;
    p ^= 1;
  }

  if (j < 128) stateH[b * 128 + j] = ((u32*)hb[p])[j];
  if (j < 256) stateC[b * 256 + j] = cst;
}

extern "C" void kernel_launch(void* const* d_in, const int* in_sizes, int n_in,
                              void* d_out, int out_size, void* d_ws, size_t ws_size,
                              hipStream_t stream){
  const float* x   = (const float*)d_in[0];
  const float* h0  = (const float*)d_in[1];
  const float* c0  = (const float*)d_in[2];
  const float* Win = (const float*)d_in[3];
  const float* Wx  = (const float*)d_in[4];
  const float* Wh  = (const float*)d_in[5];
  const float* We  = (const float*)d_in[6];
  const float* bg  = (const float*)d_in[7];
  const float* Wo  = (const float*)d_in[8];
  const float* bo  = (const float*)d_in[9];

  float* y    = (float*)d_out;
  float* hseq = y + 16777216;
  float* cseq = y + 33554432;

  // scratch inside the y-region (written only by the final gemm_y)
  char* yb = (char*)d_out;
  u16*   Gc     = (u16*)(yb);
  u16*   At     = (u16*)(yb + 33554432);
  u32*   Rres   = (u32*)(yb + 34078720);
  u32*   Rstr2  = (u32*)(yb + 34340864);
  u32*   stateH = (u32*)(yb + 34603008);
  float* stateC = (float*)(yb + 34635776);

  prep_A<<<1024, 256, 0, stream>>>(Win, Wx, We, At);
  prep_R<<<256, 512, 0, stream>>>(Wh, We, Rres, Rstr2);

  for (int c = 0; c < 4; c++){
    int t0 = c * 256;
    gemm_g<<<dim3(256, 16), 256, 0, stream>>>(x, At, Gc, bg, t0);
    scan_chunk<<<64, 512, 0, stream>>>(Rres, Rstr2, Gc, h0, c0,
                                       stateH, stateC, hseq, cseq, t0);
  }

  gemm_y<<<dim3(1024, 4), 256, 0, stream>>>(hseq, Wo, y, bo);
}

// Round 2
// 5538.188 us; speedup vs baseline: 1.7305x; 1.7305x over previous
//
#include <hip/hip_runtime.h>
#include <cstdint>
#include <cstddef>

// EP-LSTM, B=64 T=1024 D=256 H=256.  I/O dtype: FP32 (per reference file).
// Identity: pre = x@(Wx + W_in@We) + h@(Wh - We) + b   (e@We eliminated).
//
// d_ws is NOT used.  All scratch lives in the y-region of d_out
// (67,108,864 bytes), which is only written by the FINAL kernel:
//   Gc     @ y+0        : [64*256][1024] bf16 = 33,554,432 B (per-chunk G)
//   At     @ y+33554432 : [1024][256] bf16    = 524,288
//   Rres   @ y+34078720 : [64][1024] u32      = 262,144  (f16x2, k-pairs 0..63)
//   R1     @ y+34340864 : [32][1024] u32      = 131,072  (k-pairs 64..95 -> LDS)
//   R2     @ y+34471936 : [8][1024][4] u32    = 131,072  (k-pairs 96..127, streamed)
//   stateH @ y+34603008 : [64][128] u32       = 32,768   (h packed f16x2, chunk carry)
//   stateC @ y+34635776 : [64][256] f32       = 65,536   (c fp32, chunk carry)
//
// v3 scan: 1024 thr/block (16 waves, 4 waves/SIMD), 1 preact col per thread.
//   Weights per thread (128 u32) split by hard register budget (<=128 VGPR):
//     k-pairs  0..63 : w[64] in VGPRs
//     k-pairs 64..95 : private LDS slice, stride 33 u32 (8-cyc b128 floor)
//     k-pairs 96..127: streamed from L2 each step, 2 batches of 4 uint4,
//                      issued early so resident compute hides latency.
//   2 barriers/step.  v2 post-mortem: 192 reg-resident u32 spilled to scratch
//   (VGPR_Count pinned at 128) -> 2.7x regression; v3 keeps reg demand ~110.

typedef unsigned int   u32;
typedef unsigned short u16;
typedef float  f32x4  __attribute__((ext_vector_type(4)));
typedef short  bf16x8 __attribute__((ext_vector_type(8)));
typedef _Float16 h2_t __attribute__((ext_vector_type(2)));

__device__ __forceinline__ u16 f2bf(float f){
  union { float f; u32 i; } v; v.f = f;
  u32 u = v.i; u32 r = u + 0x7fffu + ((u >> 16) & 1u);
  return (u16)(r >> 16);
}
__device__ __forceinline__ float bf2f(u16 u){
  union { u32 i; float f; } v; v.i = ((u32)u) << 16; return v.f;
}
__device__ __forceinline__ h2_t as_h2(u32 u){
  union { u32 u; h2_t h; } c; c.u = u; return c.h;
}
__device__ __forceinline__ u32 pack_h2(float lo, float hi){
  h2_t h; h.x = (_Float16)lo; h.y = (_Float16)hi;
  union { h2_t h; u32 u; } c; c.h = h; return c.u;
}

#if defined(__has_builtin)
#if __has_builtin(__builtin_amdgcn_fdot2)
#define HAVE_FDOT2 1
#endif
#endif

__device__ __forceinline__ float dot2acc(u32 w, u32 h, float acc){
#ifdef HAVE_FDOT2
  return __builtin_amdgcn_fdot2(as_h2(w), as_h2(h), acc, false);
#else
  h2_t a = as_h2(w), b = as_h2(h);
  acc += (float)a.x * (float)b.x;
  acc += (float)a.y * (float)b.y;
  return acc;
#endif
}

__device__ __forceinline__ float sigf(float x){
  return __builtin_amdgcn_rcpf(1.f + __expf(-x));
}
__device__ __forceinline__ float tanhf_(float x){
  return 2.f * __builtin_amdgcn_rcpf(1.f + __expf(-2.f * x)) - 1.f;
}

// ---------- prep: At[n][k] = Wx[kg][k][j] + sum_m W_in[k][m]*We[kg][m][j] ----------
__global__ void prep_A(const float* __restrict__ Win, const float* __restrict__ Wx,
                       const float* __restrict__ We, u16* __restrict__ At){
  int n  = blockIdx.x;            // 0..1023 (kg*256 + j)
  int kg = n >> 8, j = n & 255;
  int k  = threadIdx.x;           // 0..255 = d
  __shared__ float wec[256];
  wec[k] = We[kg * 65536 + k * 256 + j];   // We[kg][m=k][j]
  __syncthreads();
  float s = Wx[kg * 65536 + k * 256 + j];
  const float* wrow = Win + k * 256;
  #pragma unroll 8
  for (int m = 0; m < 256; m++) s += wrow[m] * wec[m];
  At[n * 256 + k] = f2bf(s);
}

// ---------- prep: R = Wh - We, packed f16x2 by k-pairs ----------
// Rres [64][1024]   : k-pairs 0..63   (reg-resident in scan)
// R1   [32][1024]   : k-pairs 64..95  (LDS-resident in scan)
// R2   [8][1024][4] : k-pairs 96..127 (streamed in scan; uint4 per (q,col))
__global__ void prep_R(const float* __restrict__ Wh, const float* __restrict__ We,
                       u32* __restrict__ Rres, u32* __restrict__ R1,
                       u32* __restrict__ R2){
  int g   = blockIdx.x * 512 + threadIdx.x;   // 0..131071
  int k2  = g >> 10, col = g & 1023;
  int kg  = col >> 8, j = col & 255;
  int base = kg * 65536 + (2 * k2) * 256 + j;
  float lo = Wh[base]       - We[base];
  float hi = Wh[base + 256] - We[base + 256];
  u32 u = pack_h2(lo, hi);
  if (k2 < 64)      Rres[k2 * 1024 + col] = u;
  else if (k2 < 96) R1[(k2 - 64) * 1024 + col] = u;
  else {
    int q = (k2 - 96) >> 2, e = (k2 - 96) & 3;
    R2[(q * 1024 + col) * 4 + e] = u;
  }
}

// ---------- gemm_g: Gc[m][n] = bf16( x[srow(m)][:] ) . At[n][:] + bg[n] ----------
__global__ __launch_bounds__(256, 2) void gemm_g(
    const float* __restrict__ X, const u16* __restrict__ At,
    u16* __restrict__ Gc, const float* __restrict__ bg, int t0){
  __shared__ u16 As[64 * 256];
  __shared__ u16 Bs[64 * 256];
  int tid = threadIdx.x;
  int bm = blockIdx.x, bn = blockIdx.y;
  int r = tid >> 2, q = tid & 3;
  int m = bm * 64 + r;
  long srow = (long)(m >> 8) * 1024 + t0 + (m & 255);
  const float* ga = X + srow * 256 + q * 64;
  const u16*   gb = At + ((long)bn * 64 + r) * 256 + q * 64;
  u16* la = As + r * 256 + q * 64;
  u16* lb = Bs + r * 256 + q * 64;
  #pragma unroll
  for (int i = 0; i < 8; i++){
    float4 f0 = *(const float4*)(ga + i * 8);
    float4 f1 = *(const float4*)(ga + i * 8 + 4);
    union { u16 h[8]; uint4 v; } pk;
    pk.h[0] = f2bf(f0.x); pk.h[1] = f2bf(f0.y); pk.h[2] = f2bf(f0.z); pk.h[3] = f2bf(f0.w);
    pk.h[4] = f2bf(f1.x); pk.h[5] = f2bf(f1.y); pk.h[6] = f2bf(f1.z); pk.h[7] = f2bf(f1.w);
    *(uint4*)(la + i * 8) = pk.v;
    *(uint4*)(lb + i * 8) = *(const uint4*)(gb + i * 8);
  }
  __syncthreads();

  int wave = tid >> 6, lane = tid & 63;
  int wm = (wave & 1) * 32, wn = (wave >> 1) * 32;
  int fr = lane & 15, quad = lane >> 4;
  f32x4 acc00 = {0,0,0,0}, acc01 = {0,0,0,0}, acc10 = {0,0,0,0}, acc11 = {0,0,0,0};
  const u16* pa0 = As + (wm + fr) * 256 + quad * 8;
  const u16* pa1 = pa0 + 16 * 256;
  const u16* pb0 = Bs + (wn + fr) * 256 + quad * 8;
  const u16* pb1 = pb0 + 16 * 256;
  #pragma unroll
  for (int k = 0; k < 256; k += 32){
    bf16x8 a0 = *(const bf16x8*)(pa0 + k);
    bf16x8 a1 = *(const bf16x8*)(pa1 + k);
    bf16x8 b0 = *(const bf16x8*)(pb0 + k);
    bf16x8 b1 = *(const bf16x8*)(pb1 + k);
    acc00 = __builtin_amdgcn_mfma_f32_16x16x32_bf16(a0, b0, acc00, 0, 0, 0);
    acc01 = __builtin_amdgcn_mfma_f32_16x16x32_bf16(a0, b1, acc01, 0, 0, 0);
    acc10 = __builtin_amdgcn_mfma_f32_16x16x32_bf16(a1, b0, acc10, 0, 0, 0);
    acc11 = __builtin_amdgcn_mfma_f32_16x16x32_bf16(a1, b1, acc11, 0, 0, 0);
  }
  // C/D layout: col = lane&15, row = (lane>>4)*4 + reg  [m89-verified]
  int cr = quad * 4, cc = fr;
  long rowbase = (long)bm * 64 + wm + cr;
  long colbase = (long)bn * 64 + wn + cc;
  float bias0 = bg[colbase];
  float bias1 = bg[colbase + 16];
  #pragma unroll
  for (int e = 0; e < 4; e++){
    long r0 = rowbase + e, r1 = r0 + 16;
    Gc[r0 * 1024 + colbase]      = f2bf(acc00[e] + bias0);
    Gc[r0 * 1024 + colbase + 16] = f2bf(acc01[e] + bias1);
    Gc[r1 * 1024 + colbase]      = f2bf(acc10[e] + bias0);
    Gc[r1 * 1024 + colbase + 16] = f2bf(acc11[e] + bias1);
  }
}

// ---------- gemm_y: Y[m][n] = hseq[m][:] . W_out[:][n] + bo[n]   (M=65536,N=256) ----------
__global__ __launch_bounds__(256, 2) void gemm_y(
    const float* __restrict__ Hs, const float* __restrict__ Wo,
    float* __restrict__ Y, const float* __restrict__ bo){
  __shared__ u16 As[64 * 256];
  __shared__ u16 Bs[64 * 256];
  int tid = threadIdx.x;
  int bm = blockIdx.x, bn = blockIdx.y;
  int r = tid >> 2, q = tid & 3;
  const float* ga = Hs + ((long)bm * 64 + r) * 256 + q * 64;
  u16* la = As + r * 256 + q * 64;
  #pragma unroll
  for (int i = 0; i < 8; i++){
    float4 f0 = *(const float4*)(ga + i * 8);
    float4 f1 = *(const float4*)(ga + i * 8 + 4);
    union { u16 h[8]; uint4 v; } pk;
    pk.h[0] = f2bf(f0.x); pk.h[1] = f2bf(f0.y); pk.h[2] = f2bf(f0.z); pk.h[3] = f2bf(f0.w);
    pk.h[4] = f2bf(f1.x); pk.h[5] = f2bf(f1.y); pk.h[6] = f2bf(f1.z); pk.h[7] = f2bf(f1.w);
    *(uint4*)(la + i * 8) = pk.v;
  }
  int ncol = bn * 64 + r;
  u16* lb = Bs + r * 256 + q * 64;
  #pragma unroll 8
  for (int i = 0; i < 64; i++) lb[i] = f2bf(Wo[(q * 64 + i) * 256 + ncol]);
  __syncthreads();

  int wave = tid >> 6, lane = tid & 63;
  int wm = (wave & 1) * 32, wn = (wave >> 1) * 32;
  int fr = lane & 15, quad = lane >> 4;
  f32x4 acc00 = {0,0,0,0}, acc01 = {0,0,0,0}, acc10 = {0,0,0,0}, acc11 = {0,0,0,0};
  const u16* pa0 = As + (wm + fr) * 256 + quad * 8;
  const u16* pa1 = pa0 + 16 * 256;
  const u16* pb0 = Bs + (wn + fr) * 256 + quad * 8;
  const u16* pb1 = pb0 + 16 * 256;
  #pragma unroll
  for (int k = 0; k < 256; k += 32){
    bf16x8 a0 = *(const bf16x8*)(pa0 + k);
    bf16x8 a1 = *(const bf16x8*)(pa1 + k);
    bf16x8 b0 = *(const bf16x8*)(pb0 + k);
    bf16x8 b1 = *(const bf16x8*)(pb1 + k);
    acc00 = __builtin_amdgcn_mfma_f32_16x16x32_bf16(a0, b0, acc00, 0, 0, 0);
    acc01 = __builtin_amdgcn_mfma_f32_16x16x32_bf16(a0, b1, acc01, 0, 0, 0);
    acc10 = __builtin_amdgcn_mfma_f32_16x16x32_bf16(a1, b0, acc10, 0, 0, 0);
    acc11 = __builtin_amdgcn_mfma_f32_16x16x32_bf16(a1, b1, acc11, 0, 0, 0);
  }
  int cr = quad * 4, cc = fr;
  long rowbase = (long)bm * 64 + wm + cr;
  long colbase = (long)bn * 64 + wn + cc;
  float bias0 = bo[colbase];
  float bias1 = bo[colbase + 16];
  #pragma unroll
  for (int e = 0; e < 4; e++){
    long r0 = rowbase + e, r1 = r0 + 16;
    Y[r0 * 256 + colbase]      = acc00[e] + bias0;
    Y[r0 * 256 + colbase + 16] = acc01[e] + bias1;
    Y[r1 * 256 + colbase]      = acc10[e] + bias0;
    Y[r1 * 256 + colbase + 16] = acc11[e] + bias1;
  }
}

// ---------- recurrent scan over one 256-step chunk; one WG per batch element ----------
// 1024 threads; thread j owns preact col j.  Gate cols: f=0..255, i=256..511,
// o=512..767, g=768..1023 (gate order f,i,o,g).  f-threads own c/h state.
__global__ __launch_bounds__(1024, 4) void scan_chunk(
    const u32* __restrict__ Rres, const u32* __restrict__ R1,
    const uint4* __restrict__ R2v, const u16* __restrict__ Gc,
    const float* __restrict__ h0, const float* __restrict__ c0,
    u32* __restrict__ stateH, float* __restrict__ stateC,
    float* __restrict__ hseq, float* __restrict__ cseq, int t0){
  const int CT = 256;
  const int LSTR = 33;                        // 32 u32 payload + 1 pad: 8-cyc b128 floor
  int b = blockIdx.x;
  int j = threadIdx.x;                        // 0..1023

  __shared__ __align__(16) u32 Lw[1024 * LSTR];   // 135,168 B: k-pairs 64..95 per col
  __shared__ __align__(16) u16 hb[2][256];        // double-buffered h (f16)
  __shared__ float xi[256], xo[256], xg[256];     // gate exchange

  u32* mys = Lw + j * LSTR;

  // reg-resident: col j, k-pairs 0..63
  u32 w[64];
  #pragma unroll
  for (int kp = 0; kp < 64; kp++) w[kp] = Rres[kp * 1024 + j];
  // LDS-resident: col j, k-pairs 64..95
  #pragma unroll
  for (int i = 0; i < 32; i++) mys[i] = R1[i * 1024 + j];

  float cst = 0.f;
  if (t0 == 0){
    if (j < 128) ((u32*)hb[0])[j] = pack_h2(h0[b * 256 + 2 * j], h0[b * 256 + 2 * j + 1]);
    if (j < 256) cst = c0[b * 256 + j];
  } else {
    if (j < 128) ((u32*)hb[0])[j] = stateH[b * 128 + j];
    if (j < 256) cst = stateC[b * 256 + j];
  }

  const u16* Grow = Gc + (size_t)b * CT * 1024;
  u16 ga = Grow[j];
  __syncthreads();

  int p = 0;
  for (int tt = 0; tt < CT; tt++){
    const u16* Gn = Grow + (size_t)(tt + 1 < CT ? tt + 1 : tt) * 1024;
    u16 gan = Gn[j];

    float acc = bf2f(ga);                     // bias folded into G
    const u32* hp = (const u32*)hb[p];

    // issue streamed batch 0 (k-pairs 96..111)
    uint4 s0 = R2v[0 * 1024 + j];
    uint4 s1 = R2v[1 * 1024 + j];
    uint4 s2 = R2v[2 * 1024 + j];
    uint4 s3 = R2v[3 * 1024 + j];

    // reg-resident dot: k-pairs 0..63 (h broadcast reads, uniform address)
    #pragma unroll
    for (int qk = 0; qk < 16; qk++){
      uint4 hh = *(const uint4*)(hp + qk * 4);
      acc = dot2acc(w[4 * qk + 0], hh.x, acc);
      acc = dot2acc(w[4 * qk + 1], hh.y, acc);
      acc = dot2acc(w[4 * qk + 2], hh.z, acc);
      acc = dot2acc(w[4 * qk + 3], hh.w, acc);
    }

    // consume batch 0 (k-pairs 96..111), immediately re-issue batch 1 (112..127)
    {
      uint4 hh = *(const uint4*)(hp + 96);
      acc = dot2acc(s0.x, hh.x, acc);
      acc = dot2acc(s0.y, hh.y, acc);
      acc = dot2acc(s0.z, hh.z, acc);
      acc = dot2acc(s0.w, hh.w, acc);
      s0 = R2v[4 * 1024 + j];
      hh = *(const uint4*)(hp + 100);
      acc = dot2acc(s1.x, hh.x, acc);
      acc = dot2acc(s1.y, hh.y, acc);
      acc = dot2acc(s1.z, hh.z, acc);
      acc = dot2acc(s1.w, hh.w, acc);
      s1 = R2v[5 * 1024 + j];
      hh = *(const uint4*)(hp + 104);
      acc = dot2acc(s2.x, hh.x, acc);
      acc = dot2acc(s2.y, hh.y, acc);
      acc = dot2acc(s2.z, hh.z, acc);
      acc = dot2acc(s2.w, hh.w, acc);
      s2 = R2v[6 * 1024 + j];
      hh = *(const uint4*)(hp + 108);
      acc = dot2acc(s3.x, hh.x, acc);
      acc = dot2acc(s3.y, hh.y, acc);
      acc = dot2acc(s3.z, hh.z, acc);
      acc = dot2acc(s3.w, hh.w, acc);
      s3 = R2v[7 * 1024 + j];
    }

    // LDS-resident dot: k-pairs 64..95 (covers batch-1 latency)
    #pragma unroll
    for (int e = 0; e < 8; e++){
      uint4 ws = *(const uint4*)(mys + 4 * e);
      uint4 hh = *(const uint4*)(hp + 64 + 4 * e);
      acc = dot2acc(ws.x, hh.x, acc);
      acc = dot2acc(ws.y, hh.y, acc);
      acc = dot2acc(ws.z, hh.z, acc);
      acc = dot2acc(ws.w, hh.w, acc);
    }

    // consume batch 1 (k-pairs 112..127)
    {
      uint4 hh = *(const uint4*)(hp + 112);
      acc = dot2acc(s0.x, hh.x, acc);
      acc = dot2acc(s0.y, hh.y, acc);
      acc = dot2acc(s0.z, hh.z, acc);
      acc = dot2acc(s0.w, hh.w, acc);
      hh = *(const uint4*)(hp + 116);
      acc = dot2acc(s1.x, hh.x, acc);
      acc = dot2acc(s1.y, hh.y, acc);
      acc = dot2acc(s1.z, hh.z, acc);
      acc = dot2acc(s1.w, hh.w, acc);
      hh = *(const uint4*)(hp + 120);
      acc = dot2acc(s2.x, hh.x, acc);
      acc = dot2acc(s2.y, hh.y, acc);
      acc = dot2acc(s2.z, hh.z, acc);
      acc = dot2acc(s2.w, hh.w, acc);
      hh = *(const uint4*)(hp + 124);
      acc = dot2acc(s3.x, hh.x, acc);
      acc = dot2acc(s3.y, hh.y, acc);
      acc = dot2acc(s3.z, hh.z, acc);
      acc = dot2acc(s3.w, hh.w, acc);
    }

    // gates
    float f = 0.f;
    if (j < 256){
      f = sigf(acc);
    } else if (j < 512){
      xi[j - 256] = sigf(acc);
    } else if (j < 768){
      xo[j - 512] = sigf(acc);
    } else {
      xg[j - 768] = tanhf_(acc);
    }
    __syncthreads();

    if (j < 256){
      cst = f * cst + xi[j] * xg[j];
      float hv = xo[j] * tanhf_(cst);
      size_t orow = ((size_t)b * 1024 + t0 + tt) * 256 + j;
      hseq[orow] = hv;
      cseq[orow] = cst;
      union { _Float16 h; u16 u; } cv; cv.h = (_Float16)hv;
      hb[p ^ 1][j] = cv.u;
    }
    __syncthreads();

    ga = gan;
    p ^= 1;
  }

  if (j < 128) stateH[b * 128 + j] = ((u32*)hb[p])[j];
  if (j < 256) stateC[b * 256 + j] = cst;
}

extern "C" void kernel_launch(void* const* d_in, const int* in_sizes, int n_in,
                              void* d_out, int out_size, void* d_ws, size_t ws_size,
                              hipStream_t stream){
  const float* x   = (const float*)d_in[0];
  const float* h0  = (const float*)d_in[1];
  const float* c0  = (const float*)d_in[2];
  const float* Win = (const float*)d_in[3];
  const float* Wx  = (const float*)d_in[4];
  const float* Wh  = (const float*)d_in[5];
  const float* We  = (const float*)d_in[6];
  const float* bg  = (const float*)d_in[7];
  const float* Wo  = (const float*)d_in[8];
  const float* bo  = (const float*)d_in[9];

  float* y    = (float*)d_out;
  float* hseq = y + 16777216;
  float* cseq = y + 33554432;

  // scratch inside the y-region (written only by the final gemm_y)
  char* yb = (char*)d_out;
  u16*   Gc     = (u16*)(yb);
  u16*   At     = (u16*)(yb + 33554432);
  u32*   Rres   = (u32*)(yb + 34078720);
  u32*   R1     = (u32*)(yb + 34340864);
  u32*   R2     = (u32*)(yb + 34471936);
  u32*   stateH = (u32*)(yb + 34603008);
  float* stateC = (float*)(yb + 34635776);

  prep_A<<<1024, 256, 0, stream>>>(Win, Wx, We, At);
  prep_R<<<256, 512, 0, stream>>>(Wh, We, Rres, R1, R2);

  for (int c = 0; c < 4; c++){
    int t0 = c * 256;
    gemm_g<<<dim3(256, 16), 256, 0, stream>>>(x, At, Gc, bg, t0);
    scan_chunk<<<64, 1024, 0, stream>>>(Rres, R1, (const uint4*)R2, Gc, h0, c0,
                                        stateH, stateC, hseq, cseq, t0);
  }

  gemm_y<<<dim3(1024, 4), 256, 0, stream>>>(hseq, Wo, y, bo);
}

// Round 3
// 4719.811 us; speedup vs baseline: 2.0305x; 1.1734x over previous
//
#include <hip/hip_runtime.h>
#include <cstdint>
#include <cstddef>

// EP-LSTM, B=64 T=1024 D=256 H=256.  I/O dtype: FP32 (per reference file).
// Identity: pre = x@(Wx + W_in@We) + h@(Wh - We) + b   (e@We eliminated).
//
// d_ws is NOT used.  All scratch lives in the y-region of d_out
// (67,108,864 bytes), which is only written by the FINAL kernel:
//   Gc     @ y+0        : [64*256][1024] bf16 = 33,554,432 B (per-chunk G)
//   At     @ y+33554432 : [1024][256] bf16    = 524,288
//   Rreg   @ y+34078720 : [72][1024] u32      = 294,912  (f16x2, k-pairs 0..71, regs)
//   R1     @ y+34373632 : [32][1024] u32      = 131,072  (k-pairs 72..103 -> LDS)
//   R2     @ y+34504704 : [6][1024][4] u32    =  98,304  (k-pairs 104..127, streamed)
//   stateH @ y+34603008 : [64][128] u32       = 32,768   (h packed f16x2, chunk carry)
//   stateC @ y+34635776 : [64][256] f32       = 65,536   (c fp32, chunk carry)
//
// v4 scan: h-broadcast moved OFF the LDS pipe.  v3 post-mortem: 512 broadcast
// ds_read_b128 of h per CU-step ~= 5100 LDS-pipe cycles (the real floor; a
// broadcast b128 still writes 64x16B to the RF).  v4: each lane loads ONE u32
// of the packed-f16 h board (2 ds_read_b32/wave/step), then v_readlane
// broadcasts each h-word to an SGPR consumed directly by v_dot2_f32_f16.
// VALU becomes the floor (~2400 cyc/CU-step).  Weight split keeps ~116 live
// arch regs (v2 lesson: >budget -> scratch spill catastrophe).

typedef unsigned int   u32;
typedef unsigned short u16;
typedef float  f32x4  __attribute__((ext_vector_type(4)));
typedef short  bf16x8 __attribute__((ext_vector_type(8)));
typedef _Float16 h2_t __attribute__((ext_vector_type(2)));

__device__ __forceinline__ u16 f2bf(float f){
  union { float f; u32 i; } v; v.f = f;
  u32 u = v.i; u32 r = u + 0x7fffu + ((u >> 16) & 1u);
  return (u16)(r >> 16);
}
__device__ __forceinline__ float bf2f(u16 u){
  union { u32 i; float f; } v; v.i = ((u32)u) << 16; return v.f;
}
__device__ __forceinline__ h2_t as_h2(u32 u){
  union { u32 u; h2_t h; } c; c.u = u; return c.h;
}
__device__ __forceinline__ u32 pack_h2(float lo, float hi){
  h2_t h; h.x = (_Float16)lo; h.y = (_Float16)hi;
  union { h2_t h; u32 u; } c; c.h = h; return c.u;
}

#if defined(__has_builtin)
#if __has_builtin(__builtin_amdgcn_fdot2)
#define HAVE_FDOT2 1
#endif
#if __has_builtin(__builtin_amdgcn_readlane)
#define RDL(v, l) ((u32)__builtin_amdgcn_readlane((int)(v), (l)))
#endif
#endif
#ifndef RDL
#define RDL(v, l) ((u32)__shfl((int)(v), (l), 64))
#endif

__device__ __forceinline__ float dot2acc(u32 w, u32 h, float acc){
#ifdef HAVE_FDOT2
  return __builtin_amdgcn_fdot2(as_h2(w), as_h2(h), acc, false);
#else
  h2_t a = as_h2(w), b = as_h2(h);
  acc += (float)a.x * (float)b.x;
  acc += (float)a.y * (float)b.y;
  return acc;
#endif
}

__device__ __forceinline__ float sigf(float x){
  return __builtin_amdgcn_rcpf(1.f + __expf(-x));
}
__device__ __forceinline__ float tanhf_(float x){
  return 2.f * __builtin_amdgcn_rcpf(1.f + __expf(-2.f * x)) - 1.f;
}

// ---------- prep: At[n][k] = Wx[kg][k][j] + sum_m W_in[k][m]*We[kg][m][j] ----------
__global__ void prep_A(const float* __restrict__ Win, const float* __restrict__ Wx,
                       const float* __restrict__ We, u16* __restrict__ At){
  int n  = blockIdx.x;            // 0..1023 (kg*256 + j)
  int kg = n >> 8, j = n & 255;
  int k  = threadIdx.x;           // 0..255 = d
  __shared__ float wec[256];
  wec[k] = We[kg * 65536 + k * 256 + j];   // We[kg][m=k][j]
  __syncthreads();
  float s = Wx[kg * 65536 + k * 256 + j];
  const float* wrow = Win + k * 256;
  #pragma unroll 8
  for (int m = 0; m < 256; m++) s += wrow[m] * wec[m];
  At[n * 256 + k] = f2bf(s);
}

// ---------- prep: R = Wh - We, packed f16x2 by k-pairs ----------
// Rreg [72][1024]   : k-pairs 0..71    (reg-resident in scan)
// R1   [32][1024]   : k-pairs 72..103  (LDS-resident in scan)
// R2   [6][1024][4] : k-pairs 104..127 (streamed; uint4 per (q,col))
__global__ void prep_R(const float* __restrict__ Wh, const float* __restrict__ We,
                       u32* __restrict__ Rreg, u32* __restrict__ R1,
                       u32* __restrict__ R2){
  int g   = blockIdx.x * 512 + threadIdx.x;   // 0..131071
  int k2  = g >> 10, col = g & 1023;
  int kg  = col >> 8, j = col & 255;
  int base = kg * 65536 + (2 * k2) * 256 + j;
  float lo = Wh[base]       - We[base];
  float hi = Wh[base + 256] - We[base + 256];
  u32 u = pack_h2(lo, hi);
  if (k2 < 72)       Rreg[k2 * 1024 + col] = u;
  else if (k2 < 104) R1[(k2 - 72) * 1024 + col] = u;
  else {
    int q = (k2 - 104) >> 2, e = (k2 - 104) & 3;
    R2[(q * 1024 + col) * 4 + e] = u;
  }
}

// ---------- gemm_g: Gc[m][n] = bf16( x[srow(m)][:] ) . At[n][:] + bg[n] ----------
__global__ __launch_bounds__(256, 2) void gemm_g(
    const float* __restrict__ X, const u16* __restrict__ At,
    u16* __restrict__ Gc, const float* __restrict__ bg, int t0){
  __shared__ u16 As[64 * 256];
  __shared__ u16 Bs[64 * 256];
  int tid = threadIdx.x;
  int bm = blockIdx.x, bn = blockIdx.y;
  int r = tid >> 2, q = tid & 3;
  int m = bm * 64 + r;
  long srow = (long)(m >> 8) * 1024 + t0 + (m & 255);
  const float* ga = X + srow * 256 + q * 64;
  const u16*   gb = At + ((long)bn * 64 + r) * 256 + q * 64;
  u16* la = As + r * 256 + q * 64;
  u16* lb = Bs + r * 256 + q * 64;
  #pragma unroll
  for (int i = 0; i < 8; i++){
    float4 f0 = *(const float4*)(ga + i * 8);
    float4 f1 = *(const float4*)(ga + i * 8 + 4);
    union { u16 h[8]; uint4 v; } pk;
    pk.h[0] = f2bf(f0.x); pk.h[1] = f2bf(f0.y); pk.h[2] = f2bf(f0.z); pk.h[3] = f2bf(f0.w);
    pk.h[4] = f2bf(f1.x); pk.h[5] = f2bf(f1.y); pk.h[6] = f2bf(f1.z); pk.h[7] = f2bf(f1.w);
    *(uint4*)(la + i * 8) = pk.v;
    *(uint4*)(lb + i * 8) = *(const uint4*)(gb + i * 8);
  }
  __syncthreads();

  int wave = tid >> 6, lane = tid & 63;
  int wm = (wave & 1) * 32, wn = (wave >> 1) * 32;
  int fr = lane & 15, quad = lane >> 4;
  f32x4 acc00 = {0,0,0,0}, acc01 = {0,0,0,0}, acc10 = {0,0,0,0}, acc11 = {0,0,0,0};
  const u16* pa0 = As + (wm + fr) * 256 + quad * 8;
  const u16* pa1 = pa0 + 16 * 256;
  const u16* pb0 = Bs + (wn + fr) * 256 + quad * 8;
  const u16* pb1 = pb0 + 16 * 256;
  #pragma unroll
  for (int k = 0; k < 256; k += 32){
    bf16x8 a0 = *(const bf16x8*)(pa0 + k);
    bf16x8 a1 = *(const bf16x8*)(pa1 + k);
    bf16x8 b0 = *(const bf16x8*)(pb0 + k);
    bf16x8 b1 = *(const bf16x8*)(pb1 + k);
    acc00 = __builtin_amdgcn_mfma_f32_16x16x32_bf16(a0, b0, acc00, 0, 0, 0);
    acc01 = __builtin_amdgcn_mfma_f32_16x16x32_bf16(a0, b1, acc01, 0, 0, 0);
    acc10 = __builtin_amdgcn_mfma_f32_16x16x32_bf16(a1, b0, acc10, 0, 0, 0);
    acc11 = __builtin_amdgcn_mfma_f32_16x16x32_bf16(a1, b1, acc11, 0, 0, 0);
  }
  // C/D layout: col = lane&15, row = (lane>>4)*4 + reg  [m89-verified]
  int cr = quad * 4, cc = fr;
  long rowbase = (long)bm * 64 + wm + cr;
  long colbase = (long)bn * 64 + wn + cc;
  float bias0 = bg[colbase];
  float bias1 = bg[colbase + 16];
  #pragma unroll
  for (int e = 0; e < 4; e++){
    long r0 = rowbase + e, r1 = r0 + 16;
    Gc[r0 * 1024 + colbase]      = f2bf(acc00[e] + bias0);
    Gc[r0 * 1024 + colbase + 16] = f2bf(acc01[e] + bias1);
    Gc[r1 * 1024 + colbase]      = f2bf(acc10[e] + bias0);
    Gc[r1 * 1024 + colbase + 16] = f2bf(acc11[e] + bias1);
  }
}

// ---------- gemm_y: Y[m][n] = hseq[m][:] . W_out[:][n] + bo[n]   (M=65536,N=256) ----------
__global__ __launch_bounds__(256, 2) void gemm_y(
    const float* __restrict__ Hs, const float* __restrict__ Wo,
    float* __restrict__ Y, const float* __restrict__ bo){
  __shared__ u16 As[64 * 256];
  __shared__ u16 Bs[64 * 256];
  int tid = threadIdx.x;
  int bm = blockIdx.x, bn = blockIdx.y;
  int r = tid >> 2, q = tid & 3;
  const float* ga = Hs + ((long)bm * 64 + r) * 256 + q * 64;
  u16* la = As + r * 256 + q * 64;
  #pragma unroll
  for (int i = 0; i < 8; i++){
    float4 f0 = *(const float4*)(ga + i * 8);
    float4 f1 = *(const float4*)(ga + i * 8 + 4);
    union { u16 h[8]; uint4 v; } pk;
    pk.h[0] = f2bf(f0.x); pk.h[1] = f2bf(f0.y); pk.h[2] = f2bf(f0.z); pk.h[3] = f2bf(f0.w);
    pk.h[4] = f2bf(f1.x); pk.h[5] = f2bf(f1.y); pk.h[6] = f2bf(f1.z); pk.h[7] = f2bf(f1.w);
    *(uint4*)(la + i * 8) = pk.v;
  }
  int ncol = bn * 64 + r;
  u16* lb = Bs + r * 256 + q * 64;
  #pragma unroll 8
  for (int i = 0; i < 64; i++) lb[i] = f2bf(Wo[(q * 64 + i) * 256 + ncol]);
  __syncthreads();

  int wave = tid >> 6, lane = tid & 63;
  int wm = (wave & 1) * 32, wn = (wave >> 1) * 32;
  int fr = lane & 15, quad = lane >> 4;
  f32x4 acc00 = {0,0,0,0}, acc01 = {0,0,0,0}, acc10 = {0,0,0,0}, acc11 = {0,0,0,0};
  const u16* pa0 = As + (wm + fr) * 256 + quad * 8;
  const u16* pa1 = pa0 + 16 * 256;
  const u16* pb0 = Bs + (wn + fr) * 256 + quad * 8;
  const u16* pb1 = pb0 + 16 * 256;
  #pragma unroll
  for (int k = 0; k < 256; k += 32){
    bf16x8 a0 = *(const bf16x8*)(pa0 + k);
    bf16x8 a1 = *(const bf16x8*)(pa1 + k);
    bf16x8 b0 = *(const bf16x8*)(pb0 + k);
    bf16x8 b1 = *(const bf16x8*)(pb1 + k);
    acc00 = __builtin_amdgcn_mfma_f32_16x16x32_bf16(a0, b0, acc00, 0, 0, 0);
    acc01 = __builtin_amdgcn_mfma_f32_16x16x32_bf16(a0, b1, acc01, 0, 0, 0);
    acc10 = __builtin_amdgcn_mfma_f32_16x16x32_bf16(a1, b0, acc10, 0, 0, 0);
    acc11 = __builtin_amdgcn_mfma_f32_16x16x32_bf16(a1, b1, acc11, 0, 0, 0);
  }
  int cr = quad * 4, cc = fr;
  long rowbase = (long)bm * 64 + wm + cr;
  long colbase = (long)bn * 64 + wn + cc;
  float bias0 = bo[colbase];
  float bias1 = bo[colbase + 16];
  #pragma unroll
  for (int e = 0; e < 4; e++){
    long r0 = rowbase + e, r1 = r0 + 16;
    Y[r0 * 256 + colbase]      = acc00[e] + bias0;
    Y[r0 * 256 + colbase + 16] = acc01[e] + bias1;
    Y[r1 * 256 + colbase]      = acc10[e] + bias0;
    Y[r1 * 256 + colbase + 16] = acc11[e] + bias1;
  }
}

// ---------- recurrent scan over one 256-step chunk; one WG per batch element ----------
// 1024 threads; thread j owns preact col j.  Gate cols: f=0..255, i=256..511,
// o=512..767, g=768..1023 (gate order f,i,o,g).  f-threads own c/h state.
// h broadcast: lane l of each wave loads h-words l and 64+l (packed f16x2);
// v_readlane -> SGPR feeds v_dot2_f32_f16 directly (no per-k LDS reads).
__global__ __launch_bounds__(1024, 4) void scan_chunk(
    const u32* __restrict__ Rreg, const u32* __restrict__ R1,
    const uint4* __restrict__ R2v, const u16* __restrict__ Gc,
    const float* __restrict__ h0, const float* __restrict__ c0,
    u32* __restrict__ stateH, float* __restrict__ stateC,
    float* __restrict__ hseq, float* __restrict__ cseq, int t0){
  const int CT = 256;
  const int LSTR = 33;                        // 32 u32 payload + 1 pad
  int b = blockIdx.x;
  int j = threadIdx.x;                        // 0..1023
  int lane = j & 63;

  __shared__ __align__(16) u32 Lw[1024 * LSTR];   // 135,168 B: k-pairs 72..103 per col
  __shared__ __align__(16) u16 hb[2][256];        // double-buffered h (f16)
  __shared__ float xi[256], xo[256], xg[256];     // gate exchange

  u32* mys = Lw + j * LSTR;

  // reg-resident: col j, k-pairs 0..71
  u32 w[72];
  #pragma unroll
  for (int kp = 0; kp < 72; kp++) w[kp] = Rreg[kp * 1024 + j];
  // LDS-resident: col j, k-pairs 72..103
  #pragma unroll
  for (int i = 0; i < 32; i++) mys[i] = R1[i * 1024 + j];

  float cst = 0.f;
  if (t0 == 0){
    if (j < 128) ((u32*)hb[0])[j] = pack_h2(h0[b * 256 + 2 * j], h0[b * 256 + 2 * j + 1]);
    if (j < 256) cst = c0[b * 256 + j];
  } else {
    if (j < 128) ((u32*)hb[0])[j] = stateH[b * 128 + j];
    if (j < 256) cst = stateC[b * 256 + j];
  }

  const u16* Grow = Gc + (size_t)b * CT * 1024;
  u16 ga = Grow[j];
  __syncthreads();

  int p = 0;
  for (int tt = 0; tt < CT; tt++){
    const u16* Gn = Grow + (size_t)(tt + 1 < CT ? tt + 1 : tt) * 1024;
    u16 gan = Gn[j];

    // streamed weights: k-pairs 104..127 (6 uint4; L1/L2-hot, same addr each step)
    uint4 r0 = R2v[0 * 1024 + j];
    uint4 r1 = R2v[1 * 1024 + j];
    uint4 r2 = R2v[2 * 1024 + j];
    uint4 r3 = R2v[3 * 1024 + j];
    uint4 r4 = R2v[4 * 1024 + j];
    uint4 r5 = R2v[5 * 1024 + j];

    // wave-local h gather: lane l holds h-words l (hA) and 64+l (hB)
    u32 hA = ((const u32*)hb[p])[lane];
    u32 hB = ((const u32*)hb[p])[64 + lane];

    float acc0 = bf2f(ga), acc1 = 0.f;        // bias folded into G

    // reg dot: k-pairs 0..63 via readlane(hA)
    #pragma unroll
    for (int kp = 0; kp < 64; kp += 2){
      acc0 = dot2acc(w[kp],     RDL(hA, kp),     acc0);
      acc1 = dot2acc(w[kp + 1], RDL(hA, kp + 1), acc1);
    }
    // reg dot: k-pairs 64..71 via readlane(hB lanes 0..7)
    #pragma unroll
    for (int kp = 64; kp < 72; kp += 2){
      acc0 = dot2acc(w[kp],     RDL(hB, kp - 64), acc0);
      acc1 = dot2acc(w[kp + 1], RDL(hB, kp - 63), acc1);
    }
    // LDS dot: k-pairs 72..103 (hB lanes 8..39)
    #pragma unroll
    for (int e = 0; e < 8; e++){
      uint4 ws = *(const uint4*)(mys + 4 * e);
      acc0 = dot2acc(ws.x, RDL(hB,  8 + 4 * e), acc0);
      acc1 = dot2acc(ws.y, RDL(hB,  9 + 4 * e), acc1);
      acc0 = dot2acc(ws.z, RDL(hB, 10 + 4 * e), acc0);
      acc1 = dot2acc(ws.w, RDL(hB, 11 + 4 * e), acc1);
    }
    // streamed dot: k-pairs 104..127 (hB lanes 40..63)
    acc0 = dot2acc(r0.x, RDL(hB, 40), acc0);
    acc1 = dot2acc(r0.y, RDL(hB, 41), acc1);
    acc0 = dot2acc(r0.z, RDL(hB, 42), acc0);
    acc1 = dot2acc(r0.w, RDL(hB, 43), acc1);
    acc0 = dot2acc(r1.x, RDL(hB, 44), acc0);
    acc1 = dot2acc(r1.y, RDL(hB, 45), acc1);
    acc0 = dot2acc(r1.z, RDL(hB, 46), acc0);
    acc1 = dot2acc(r1.w, RDL(hB, 47), acc1);
    acc0 = dot2acc(r2.x, RDL(hB, 48), acc0);
    acc1 = dot2acc(r2.y, RDL(hB, 49), acc1);
    acc0 = dot2acc(r2.z, RDL(hB, 50), acc0);
    acc1 = dot2acc(r2.w, RDL(hB, 51), acc1);
    acc0 = dot2acc(r3.x, RDL(hB, 52), acc0);
    acc1 = dot2acc(r3.y, RDL(hB, 53), acc1);
    acc0 = dot2acc(r3.z, RDL(hB, 54), acc0);
    acc1 = dot2acc(r3.w, RDL(hB, 55), acc1);
    acc0 = dot2acc(r4.x, RDL(hB, 56), acc0);
    acc1 = dot2acc(r4.y, RDL(hB, 57), acc1);
    acc0 = dot2acc(r4.z, RDL(hB, 58), acc0);
    acc1 = dot2acc(r4.w, RDL(hB, 59), acc1);
    acc0 = dot2acc(r5.x, RDL(hB, 60), acc0);
    acc1 = dot2acc(r5.y, RDL(hB, 61), acc1);
    acc0 = dot2acc(r5.z, RDL(hB, 62), acc0);
    acc1 = dot2acc(r5.w, RDL(hB, 63), acc1);

    float acc = acc0 + acc1;

    // gates
    float f = 0.f;
    if (j < 256){
      f = sigf(acc);
    } else if (j < 512){
      xi[j - 256] = sigf(acc);
    } else if (j < 768){
      xo[j - 512] = sigf(acc);
    } else {
      xg[j - 768] = tanhf_(acc);
    }
    __syncthreads();

    if (j < 256){
      cst = f * cst + xi[j] * xg[j];
      float hv = xo[j] * tanhf_(cst);
      size_t orow = ((size_t)b * 1024 + t0 + tt) * 256 + j;
      hseq[orow] = hv;
      cseq[orow] = cst;
      union { _Float16 h; u16 u; } cv; cv.h = (_Float16)hv;
      hb[p ^ 1][j] = cv.u;
    }
    __syncthreads();

    ga = gan;
    p ^= 1;
  }

  if (j < 128) stateH[b * 128 + j] = ((u32*)hb[p])[j];
  if (j < 256) stateC[b * 256 + j] = cst;
}

extern "C" void kernel_launch(void* const* d_in, const int* in_sizes, int n_in,
                              void* d_out, int out_size, void* d_ws, size_t ws_size,
                              hipStream_t stream){
  const float* x   = (const float*)d_in[0];
  const float* h0  = (const float*)d_in[1];
  const float* c0  = (const float*)d_in[2];
  const float* Win = (const float*)d_in[3];
  const float* Wx  = (const float*)d_in[4];
  const float* Wh  = (const float*)d_in[5];
  const float* We  = (const float*)d_in[6];
  const float* bg  = (const float*)d_in[7];
  const float* Wo  = (const float*)d_in[8];
  const float* bo  = (const float*)d_in[9];

  float* y    = (float*)d_out;
  float* hseq = y + 16777216;
  float* cseq = y + 33554432;

  // scratch inside the y-region (written only by the final gemm_y)
  char* yb = (char*)d_out;
  u16*   Gc     = (u16*)(yb);
  u16*   At     = (u16*)(yb + 33554432);
  u32*   Rreg   = (u32*)(yb + 34078720);
  u32*   R1     = (u32*)(yb + 34373632);
  u32*   R2     = (u32*)(yb + 34504704);
  u32*   stateH = (u32*)(yb + 34603008);
  float* stateC = (float*)(yb + 34635776);

  prep_A<<<1024, 256, 0, stream>>>(Win, Wx, We, At);
  prep_R<<<256, 512, 0, stream>>>(Wh, We, Rreg, R1, R2);

  for (int c = 0; c < 4; c++){
    int t0 = c * 256;
    gemm_g<<<dim3(256, 16), 256, 0, stream>>>(x, At, Gc, bg, t0);
    scan_chunk<<<64, 1024, 0, stream>>>(Rreg, R1, (const uint4*)R2, Gc, h0, c0,
                                        stateH, stateC, hseq, cseq, t0);
  }

  gemm_y<<<dim3(1024, 4), 256, 0, stream>>>(hseq, Wo, y, bo);
}

// Round 4
// 3447.498 us; speedup vs baseline: 2.7799x; 1.3691x over previous
//
#include <hip/hip_runtime.h>
#include <cstdint>
#include <cstddef>

// EP-LSTM, B=64 T=1024 D=256 H=256.  I/O dtype: FP32 (per reference file).
// Identity: pre = x@(Wx + W_in@We) + h@(Wh - We) + b   (e@We eliminated).
//
// d_ws is NOT used.  All scratch lives in the y-region of d_out
// (67,108,864 bytes), which is only written by the FINAL kernel:
//   Gc     @ y+0        : [64*256][1024] bf16 = 33,554,432 B (per-chunk G)
//   At     @ y+33554432 : [1024][256] bf16    = 524,288
//   Rreg   @ y+34078720 : [64][1024] u32      = 262,144  (f16x2, k-pairs 0..63 -> VGPR)
//   R1     @ y+34340864 : [32][1024] u32      = 131,072  (k-pairs 64..95 -> LDS)
//   R2     @ y+34471936 : [8][1024][4] u32    = 131,072  (k-pairs 96..127, streamed)
//
// v5 scan: ONE barrier/step, h never leaves registers.
//   v4 post-mortem: 2 barriers/step x 16 waves + h round trip through LDS
//   (gates->xch->f-threads->pack->hb->loads) = ~5300 stall cyc/step; plus
//   w[72] AGPR-shadow (VGPR_Count=64) = accvgpr_read VALU tax.
//   v5: per-lane replicated state: lane l of EVERY wave owns h-words l and
//   64+l (f16x2) and c for dims {2l,2l+1,128+2l,129+2l}.  Per step each
//   thread publishes ONE gate f32 to dbuf LDS; one barrier; every lane reads
//   8 gate b64-quads and updates c/h locally (bit-identical across waves).
//   Wave 0 stores hseq/cseq (also the chunk carry).  Weights: w[64] VGPR +
//   32 kp XOR-swizzled LDS + 32 kp streamed (2x4 uint4) -> ~110 live regs.

typedef unsigned int   u32;
typedef unsigned short u16;
typedef float  f32x4  __attribute__((ext_vector_type(4)));
typedef short  bf16x8 __attribute__((ext_vector_type(8)));
typedef _Float16 h2_t __attribute__((ext_vector_type(2)));

__device__ __forceinline__ u16 f2bf(float f){
  union { float f; u32 i; } v; v.f = f;
  u32 u = v.i; u32 r = u + 0x7fffu + ((u >> 16) & 1u);
  return (u16)(r >> 16);
}
__device__ __forceinline__ float bf2f(u16 u){
  union { u32 i; float f; } v; v.i = ((u32)u) << 16; return v.f;
}
__device__ __forceinline__ h2_t as_h2(u32 u){
  union { u32 u; h2_t h; } c; c.u = u; return c.h;
}
__device__ __forceinline__ u32 pack_h2(float lo, float hi){
  h2_t h; h.x = (_Float16)lo; h.y = (_Float16)hi;
  union { h2_t h; u32 u; } c; c.h = h; return c.u;
}

#if defined(__has_builtin)
#if __has_builtin(__builtin_amdgcn_fdot2)
#define HAVE_FDOT2 1
#endif
#if __has_builtin(__builtin_amdgcn_readlane)
#define RDL(v, l) ((u32)__builtin_amdgcn_readlane((int)(v), (l)))
#endif
#endif
#ifndef RDL
#define RDL(v, l) ((u32)__shfl((int)(v), (l), 64))
#endif

__device__ __forceinline__ float dot2acc(u32 w, u32 h, float acc){
#ifdef HAVE_FDOT2
  return __builtin_amdgcn_fdot2(as_h2(w), as_h2(h), acc, false);
#else
  h2_t a = as_h2(w), b = as_h2(h);
  acc += (float)a.x * (float)b.x;
  acc += (float)a.y * (float)b.y;
  return acc;
#endif
}

__device__ __forceinline__ float sigf(float x){
  return __builtin_amdgcn_rcpf(1.f + __expf(-x));
}
__device__ __forceinline__ float tanhf_(float x){
  return 2.f * __builtin_amdgcn_rcpf(1.f + __expf(-2.f * x)) - 1.f;
}

// ---------- prep: At[n][k] = Wx[kg][k][j] + sum_m W_in[k][m]*We[kg][m][j] ----------
__global__ void prep_A(const float* __restrict__ Win, const float* __restrict__ Wx,
                       const float* __restrict__ We, u16* __restrict__ At){
  int n  = blockIdx.x;            // 0..1023 (kg*256 + j)
  int kg = n >> 8, j = n & 255;
  int k  = threadIdx.x;           // 0..255 = d
  __shared__ float wec[256];
  wec[k] = We[kg * 65536 + k * 256 + j];   // We[kg][m=k][j]
  __syncthreads();
  float s = Wx[kg * 65536 + k * 256 + j];
  const float* wrow = Win + k * 256;
  #pragma unroll 8
  for (int m = 0; m < 256; m++) s += wrow[m] * wec[m];
  At[n * 256 + k] = f2bf(s);
}

// ---------- prep: R = Wh - We, packed f16x2 by k-pairs ----------
// Rreg [64][1024]   : k-pairs 0..63   (VGPR-resident in scan)
// R1   [32][1024]   : k-pairs 64..95  (LDS-resident in scan)
// R2   [8][1024][4] : k-pairs 96..127 (streamed; uint4 per (q,col))
__global__ void prep_R(const float* __restrict__ Wh, const float* __restrict__ We,
                       u32* __restrict__ Rreg, u32* __restrict__ R1,
                       u32* __restrict__ R2){
  int g   = blockIdx.x * 512 + threadIdx.x;   // 0..131071
  int k2  = g >> 10, col = g & 1023;
  int kg  = col >> 8, j = col & 255;
  int base = kg * 65536 + (2 * k2) * 256 + j;
  float lo = Wh[base]       - We[base];
  float hi = Wh[base + 256] - We[base + 256];
  u32 u = pack_h2(lo, hi);
  if (k2 < 64)      Rreg[k2 * 1024 + col] = u;
  else if (k2 < 96) R1[(k2 - 64) * 1024 + col] = u;
  else {
    int q = (k2 - 96) >> 2, e = (k2 - 96) & 3;
    R2[(q * 1024 + col) * 4 + e] = u;
  }
}

// ---------- gemm_g: Gc[m][n] = bf16( x[srow(m)][:] ) . At[n][:] + bg[n] ----------
__global__ __launch_bounds__(256, 2) void gemm_g(
    const float* __restrict__ X, const u16* __restrict__ At,
    u16* __restrict__ Gc, const float* __restrict__ bg, int t0){
  __shared__ u16 As[64 * 256];
  __shared__ u16 Bs[64 * 256];
  int tid = threadIdx.x;
  int bm = blockIdx.x, bn = blockIdx.y;
  int r = tid >> 2, q = tid & 3;
  int m = bm * 64 + r;
  long srow = (long)(m >> 8) * 1024 + t0 + (m & 255);
  const float* ga = X + srow * 256 + q * 64;
  const u16*   gb = At + ((long)bn * 64 + r) * 256 + q * 64;
  u16* la = As + r * 256 + q * 64;
  u16* lb = Bs + r * 256 + q * 64;
  #pragma unroll
  for (int i = 0; i < 8; i++){
    float4 f0 = *(const float4*)(ga + i * 8);
    float4 f1 = *(const float4*)(ga + i * 8 + 4);
    union { u16 h[8]; uint4 v; } pk;
    pk.h[0] = f2bf(f0.x); pk.h[1] = f2bf(f0.y); pk.h[2] = f2bf(f0.z); pk.h[3] = f2bf(f0.w);
    pk.h[4] = f2bf(f1.x); pk.h[5] = f2bf(f1.y); pk.h[6] = f2bf(f1.z); pk.h[7] = f2bf(f1.w);
    *(uint4*)(la + i * 8) = pk.v;
    *(uint4*)(lb + i * 8) = *(const uint4*)(gb + i * 8);
  }
  __syncthreads();

  int wave = tid >> 6, lane = tid & 63;
  int wm = (wave & 1) * 32, wn = (wave >> 1) * 32;
  int fr = lane & 15, quad = lane >> 4;
  f32x4 acc00 = {0,0,0,0}, acc01 = {0,0,0,0}, acc10 = {0,0,0,0}, acc11 = {0,0,0,0};
  const u16* pa0 = As + (wm + fr) * 256 + quad * 8;
  const u16* pa1 = pa0 + 16 * 256;
  const u16* pb0 = Bs + (wn + fr) * 256 + quad * 8;
  const u16* pb1 = pb0 + 16 * 256;
  #pragma unroll
  for (int k = 0; k < 256; k += 32){
    bf16x8 a0 = *(const bf16x8*)(pa0 + k);
    bf16x8 a1 = *(const bf16x8*)(pa1 + k);
    bf16x8 b0 = *(const bf16x8*)(pb0 + k);
    bf16x8 b1 = *(const bf16x8*)(pb1 + k);
    acc00 = __builtin_amdgcn_mfma_f32_16x16x32_bf16(a0, b0, acc00, 0, 0, 0);
    acc01 = __builtin_amdgcn_mfma_f32_16x16x32_bf16(a0, b1, acc01, 0, 0, 0);
    acc10 = __builtin_amdgcn_mfma_f32_16x16x32_bf16(a1, b0, acc10, 0, 0, 0);
    acc11 = __builtin_amdgcn_mfma_f32_16x16x32_bf16(a1, b1, acc11, 0, 0, 0);
  }
  // C/D layout: col = lane&15, row = (lane>>4)*4 + reg  [m89-verified]
  int cr = quad * 4, cc = fr;
  long rowbase = (long)bm * 64 + wm + cr;
  long colbase = (long)bn * 64 + wn + cc;
  float bias0 = bg[colbase];
  float bias1 = bg[colbase + 16];
  #pragma unroll
  for (int e = 0; e < 4; e++){
    long r0 = rowbase + e, r1 = r0 + 16;
    Gc[r0 * 1024 + colbase]      = f2bf(acc00[e] + bias0);
    Gc[r0 * 1024 + colbase + 16] = f2bf(acc01[e] + bias1);
    Gc[r1 * 1024 + colbase]      = f2bf(acc10[e] + bias0);
    Gc[r1 * 1024 + colbase + 16] = f2bf(acc11[e] + bias1);
  }
}

// ---------- gemm_y: Y[m][n] = hseq[m][:] . W_out[:][n] + bo[n]   (M=65536,N=256) ----------
__global__ __launch_bounds__(256, 2) void gemm_y(
    const float* __restrict__ Hs, const float* __restrict__ Wo,
    float* __restrict__ Y, const float* __restrict__ bo){
  __shared__ u16 As[64 * 256];
  __shared__ u16 Bs[64 * 256];
  int tid = threadIdx.x;
  int bm = blockIdx.x, bn = blockIdx.y;
  int r = tid >> 2, q = tid & 3;
  const float* ga = Hs + ((long)bm * 64 + r) * 256 + q * 64;
  u16* la = As + r * 256 + q * 64;
  #pragma unroll
  for (int i = 0; i < 8; i++){
    float4 f0 = *(const float4*)(ga + i * 8);
    float4 f1 = *(const float4*)(ga + i * 8 + 4);
    union { u16 h[8]; uint4 v; } pk;
    pk.h[0] = f2bf(f0.x); pk.h[1] = f2bf(f0.y); pk.h[2] = f2bf(f0.z); pk.h[3] = f2bf(f0.w);
    pk.h[4] = f2bf(f1.x); pk.h[5] = f2bf(f1.y); pk.h[6] = f2bf(f1.z); pk.h[7] = f2bf(f1.w);
    *(uint4*)(la + i * 8) = pk.v;
  }
  int ncol = bn * 64 + r;
  u16* lb = Bs + r * 256 + q * 64;
  #pragma unroll 8
  for (int i = 0; i < 64; i++) lb[i] = f2bf(Wo[(q * 64 + i) * 256 + ncol]);
  __syncthreads();

  int wave = tid >> 6, lane = tid & 63;
  int wm = (wave & 1) * 32, wn = (wave >> 1) * 32;
  int fr = lane & 15, quad = lane >> 4;
  f32x4 acc00 = {0,0,0,0}, acc01 = {0,0,0,0}, acc10 = {0,0,0,0}, acc11 = {0,0,0,0};
  const u16* pa0 = As + (wm + fr) * 256 + quad * 8;
  const u16* pa1 = pa0 + 16 * 256;
  const u16* pb0 = Bs + (wn + fr) * 256 + quad * 8;
  const u16* pb1 = pb0 + 16 * 256;
  #pragma unroll
  for (int k = 0; k < 256; k += 32){
    bf16x8 a0 = *(const bf16x8*)(pa0 + k);
    bf16x8 a1 = *(const bf16x8*)(pa1 + k);
    bf16x8 b0 = *(const bf16x8*)(pb0 + k);
    bf16x8 b1 = *(const bf16x8*)(pb1 + k);
    acc00 = __builtin_amdgcn_mfma_f32_16x16x32_bf16(a0, b0, acc00, 0, 0, 0);
    acc01 = __builtin_amdgcn_mfma_f32_16x16x32_bf16(a0, b1, acc01, 0, 0, 0);
    acc10 = __builtin_amdgcn_mfma_f32_16x16x32_bf16(a1, b0, acc10, 0, 0, 0);
    acc11 = __builtin_amdgcn_mfma_f32_16x16x32_bf16(a1, b1, acc11, 0, 0, 0);
  }
  int cr = quad * 4, cc = fr;
  long rowbase = (long)bm * 64 + wm + cr;
  long colbase = (long)bn * 64 + wn + cc;
  float bias0 = bo[colbase];
  float bias1 = bo[colbase + 16];
  #pragma unroll
  for (int e = 0; e < 4; e++){
    long r0 = rowbase + e, r1 = r0 + 16;
    Y[r0 * 256 + colbase]      = acc00[e] + bias0;
    Y[r0 * 256 + colbase + 16] = acc01[e] + bias1;
    Y[r1 * 256 + colbase]      = acc10[e] + bias0;
    Y[r1 * 256 + colbase + 16] = acc11[e] + bias1;
  }
}

// ---------- recurrent scan over one 256-step chunk; one WG per batch element ----------
// 1024 threads; thread j owns preact col j (gate j>>8, dim j&255).
// Per-lane replicated state: lane l holds h-words l and 64+l and c for dims
// {2l, 2l+1, 128+2l, 129+2l}.  ONE __syncthreads per step.
__global__ __launch_bounds__(1024, 4) void scan_chunk(
    const u32* __restrict__ Rreg, const u32* __restrict__ R1,
    const uint4* __restrict__ R2v, const u16* __restrict__ Gc,
    const float* __restrict__ h0, const float* __restrict__ c0,
    float* __restrict__ hseq, float* __restrict__ cseq, int t0){
  const int CT = 256;
  int b = blockIdx.x;
  int j = threadIdx.x;                        // 0..1023
  int l = j & 63;
  int wv = j >> 6;
  int sw = (j & 7);                           // XOR-swizzle key for LDS slice

  __shared__ __align__(16) u32 Lw[1024 * 32];     // 131,072 B: k-pairs 64..95, swizzled
  __shared__ float xg2[2][1024];                  // gate exchange, double-buffered

  u32* mys = Lw + j * 32;

  // VGPR-resident: col j, k-pairs 0..63 (all consumed against hA)
  u32 w[64];
  #pragma unroll
  for (int kp = 0; kp < 64; kp++) w[kp] = Rreg[kp * 1024 + j];
  // LDS-resident: col j, k-pairs 64..95, stored at XOR-swizzled quad positions
  #pragma unroll
  for (int e = 0; e < 8; e++){
    uint4 t;
    t.x = R1[(4 * e + 0) * 1024 + j];
    t.y = R1[(4 * e + 1) * 1024 + j];
    t.z = R1[(4 * e + 2) * 1024 + j];
    t.w = R1[(4 * e + 3) * 1024 + j];
    *(uint4*)(mys + ((e ^ sw) << 2)) = t;
  }

  // state init (lane-replicated): h-words l / 64+l, c quad
  u32 hA, hB;
  float cA0, cA1, cB0, cB1;
  if (t0 == 0){
    const float* hp = h0 + b * 256;
    const float* cp = c0 + b * 256;
    hA = pack_h2(hp[2 * l], hp[2 * l + 1]);
    hB = pack_h2(hp[128 + 2 * l], hp[129 + 2 * l]);
    cA0 = cp[2 * l]; cA1 = cp[2 * l + 1];
    cB0 = cp[128 + 2 * l]; cB1 = cp[129 + 2 * l];
  } else {
    size_t prow = ((size_t)b * 1024 + t0 - 1) * 256;
    hA = pack_h2(hseq[prow + 2 * l], hseq[prow + 2 * l + 1]);
    hB = pack_h2(hseq[prow + 128 + 2 * l], hseq[prow + 129 + 2 * l]);
    cA0 = cseq[prow + 2 * l]; cA1 = cseq[prow + 2 * l + 1];
    cB0 = cseq[prow + 128 + 2 * l]; cB1 = cseq[prow + 129 + 2 * l];
  }

  const u16* Grow = Gc + (size_t)b * CT * 1024;
  u16 ga = Grow[j];
  __syncthreads();

  int pp = 0;
  for (int tt = 0; tt < CT; tt++){
    // stream batch A (k-pairs 96..111)
    uint4 s0 = R2v[0 * 1024 + j];
    uint4 s1 = R2v[1 * 1024 + j];
    uint4 s2 = R2v[2 * 1024 + j];
    uint4 s3 = R2v[3 * 1024 + j];
    // prefetch next-step G
    const u16* Gn = Grow + (size_t)(tt + 1 < CT ? tt + 1 : tt) * 1024;
    u16 gan = Gn[j];

    float a0 = bf2f(ga), a1 = 0.f;            // bias folded into G

    // k-pairs 0..63: VGPR weights vs readlane(hA)
    #pragma unroll
    for (int kp = 0; kp < 64; kp += 2){
      a0 = dot2acc(w[kp],     RDL(hA, kp),     a0);
      a1 = dot2acc(w[kp + 1], RDL(hA, kp + 1), a1);
    }
    // k-pairs 64..95: LDS weights (swizzled) vs readlane(hB lanes 0..31)
    #pragma unroll
    for (int e = 0; e < 8; e++){
      uint4 ws = *(const uint4*)(mys + ((e ^ sw) << 2));
      a0 = dot2acc(ws.x, RDL(hB, 4 * e + 0), a0);
      a1 = dot2acc(ws.y, RDL(hB, 4 * e + 1), a1);
      a0 = dot2acc(ws.z, RDL(hB, 4 * e + 2), a0);
      a1 = dot2acc(ws.w, RDL(hB, 4 * e + 3), a1);
    }
    // stream batch B issue (k-pairs 112..127)
    uint4 s4 = R2v[4 * 1024 + j];
    uint4 s5 = R2v[5 * 1024 + j];
    uint4 s6 = R2v[6 * 1024 + j];
    uint4 s7 = R2v[7 * 1024 + j];
    // consume batch A: k-pairs 96..111 (hB lanes 32..47)
    a0 = dot2acc(s0.x, RDL(hB, 32), a0);
    a1 = dot2acc(s0.y, RDL(hB, 33), a1);
    a0 = dot2acc(s0.z, RDL(hB, 34), a0);
    a1 = dot2acc(s0.w, RDL(hB, 35), a1);
    a0 = dot2acc(s1.x, RDL(hB, 36), a0);
    a1 = dot2acc(s1.y, RDL(hB, 37), a1);
    a0 = dot2acc(s1.z, RDL(hB, 38), a0);
    a1 = dot2acc(s1.w, RDL(hB, 39), a1);
    a0 = dot2acc(s2.x, RDL(hB, 40), a0);
    a1 = dot2acc(s2.y, RDL(hB, 41), a1);
    a0 = dot2acc(s2.z, RDL(hB, 42), a0);
    a1 = dot2acc(s2.w, RDL(hB, 43), a1);
    a0 = dot2acc(s3.x, RDL(hB, 44), a0);
    a1 = dot2acc(s3.y, RDL(hB, 45), a1);
    a0 = dot2acc(s3.z, RDL(hB, 46), a0);
    a1 = dot2acc(s3.w, RDL(hB, 47), a1);
    // consume batch B: k-pairs 112..127 (hB lanes 48..63)
    a0 = dot2acc(s4.x, RDL(hB, 48), a0);
    a1 = dot2acc(s4.y, RDL(hB, 49), a1);
    a0 = dot2acc(s4.z, RDL(hB, 50), a0);
    a1 = dot2acc(s4.w, RDL(hB, 51), a1);
    a0 = dot2acc(s5.x, RDL(hB, 52), a0);
    a1 = dot2acc(s5.y, RDL(hB, 53), a1);
    a0 = dot2acc(s5.z, RDL(hB, 54), a0);
    a1 = dot2acc(s5.w, RDL(hB, 55), a1);
    a0 = dot2acc(s6.x, RDL(hB, 56), a0);
    a1 = dot2acc(s6.y, RDL(hB, 57), a1);
    a0 = dot2acc(s6.z, RDL(hB, 58), a0);
    a1 = dot2acc(s6.w, RDL(hB, 59), a1);
    a0 = dot2acc(s7.x, RDL(hB, 60), a0);
    a1 = dot2acc(s7.y, RDL(hB, 61), a1);
    a0 = dot2acc(s7.z, RDL(hB, 62), a0);
    a1 = dot2acc(s7.w, RDL(hB, 63), a1);

    float acc = a0 + a1;
    // gate (wave-uniform branch: waves 0..11 sigmoid, 12..15 tanh)
    float gv = (j < 768) ? sigf(acc) : tanhf_(acc);
    xg2[pp][j] = gv;
    __syncthreads();

    // replicated c/h update from gate quads (gate order f,i,o,g)
    const float* xb = xg2[pp];
    float2 f1_ = *(const float2*)(xb +   0 + 2 * l);
    float2 i1_ = *(const float2*)(xb + 256 + 2 * l);
    float2 o1_ = *(const float2*)(xb + 512 + 2 * l);
    float2 g1_ = *(const float2*)(xb + 768 + 2 * l);
    float2 f2_ = *(const float2*)(xb + 128 + 2 * l);
    float2 i2_ = *(const float2*)(xb + 384 + 2 * l);
    float2 o2_ = *(const float2*)(xb + 640 + 2 * l);
    float2 g2_ = *(const float2*)(xb + 896 + 2 * l);

    cA0 = f1_.x * cA0 + i1_.x * g1_.x;  float h0v = o1_.x * tanhf_(cA0);
    cA1 = f1_.y * cA1 + i1_.y * g1_.y;  float h1v = o1_.y * tanhf_(cA1);
    cB0 = f2_.x * cB0 + i2_.x * g2_.x;  float h2v = o2_.x * tanhf_(cB0);
    cB1 = f2_.y * cB1 + i2_.y * g2_.y;  float h3v = o2_.y * tanhf_(cB1);
    hA = pack_h2(h0v, h1v);
    hB = pack_h2(h2v, h3v);

    if (wv == 0){
      size_t orow = ((size_t)b * 1024 + t0 + tt) * 256;
      float2 vh0 = {h0v, h1v}, vh1 = {h2v, h3v};
      float2 vc0 = {cA0, cA1}, vc1 = {cB0, cB1};
      *(float2*)(hseq + orow + 2 * l)       = vh0;
      *(float2*)(hseq + orow + 128 + 2 * l) = vh1;
      *(float2*)(cseq + orow + 2 * l)       = vc0;
      *(float2*)(cseq + orow + 128 + 2 * l) = vc1;
    }

    ga = gan;
    pp ^= 1;
  }
}

extern "C" void kernel_launch(void* const* d_in, const int* in_sizes, int n_in,
                              void* d_out, int out_size, void* d_ws, size_t ws_size,
                              hipStream_t stream){
  const float* x   = (const float*)d_in[0];
  const float* h0  = (const float*)d_in[1];
  const float* c0  = (const float*)d_in[2];
  const float* Win = (const float*)d_in[3];
  const float* Wx  = (const float*)d_in[4];
  const float* Wh  = (const float*)d_in[5];
  const float* We  = (const float*)d_in[6];
  const float* bg  = (const float*)d_in[7];
  const float* Wo  = (const float*)d_in[8];
  const float* bo  = (const float*)d_in[9];

  float* y    = (float*)d_out;
  float* hseq = y + 16777216;
  float* cseq = y + 33554432;

  // scratch inside the y-region (written only by the final gemm_y)
  char* yb = (char*)d_out;
  u16*   Gc     = (u16*)(yb);
  u16*   At     = (u16*)(yb + 33554432);
  u32*   Rreg   = (u32*)(yb + 34078720);
  u32*   R1     = (u32*)(yb + 34340864);
  u32*   R2     = (u32*)(yb + 34471936);

  prep_A<<<1024, 256, 0, stream>>>(Win, Wx, We, At);
  prep_R<<<256, 512, 0, stream>>>(Wh, We, Rreg, R1, R2);

  for (int c = 0; c < 4; c++){
    int t0 = c * 256;
    gemm_g<<<dim3(256, 16), 256, 0, stream>>>(x, At, Gc, bg, t0);
    scan_chunk<<<64, 1024, 0, stream>>>(Rreg, R1, (const uint4*)R2, Gc, h0, c0,
                                        hseq, cseq, t0);
  }

  gemm_y<<<dim3(1024, 4), 256, 0, stream>>>(hseq, Wo, y, bo);
}